// Round 21
// baseline (81.528 us; speedup 1.0000x reference)
//
#include <hip/hip_runtime.h>
#include <math.h>

#define PH 7
#define PW 7
#define B_ 4
#define C_ 256
#define H_ 50
#define W_ 50
#define R_ 256
#define S_ (H_ * W_)     // 2500
#define NCELL (PH * PW)  // 49
#define SSTR 65          // strip row stride: (p*65)%32 = p -> distinct banks

// SINGLE dispatch, direct (B,C,H,W). R20 + full 7-band interleaved walk:
// all 7 row-bands step together -> 7 independent loads in flight (R20: 4).
// Main loop = nmin unclamped steps (7 loads + 7 fmax + 7 ptr bumps); tail
// (<=2 iters, wave-uniform) finishes taller bands via exact per-band counts.
// R19 counters justify this: VALUBusy 42% / occ 50% after the conflict fix
// -> the walk is LATENCY-bound; MLP is the remaining lever.
// Proven machinery unchanged: adaptive 4/2/1-ch packing by roi width,
// scalar band bounds, clamped dup cols (max-safe), stride-65 wave-private
// strip, lgkmcnt+sched_barrier fences, 196 B contiguous stores.
__global__ void __launch_bounds__(256, 8)
roi_pool_pack4(const float* __restrict__ features, const int* __restrict__ rois,
               float* __restrict__ out) {
    __shared__ float strip[4][PH][SSTR];  // wave-private strips, 7280 B
    const int bx   = blockIdx.x;
    const int r    = bx >> 4;             // 0..255
    const int wid  = threadIdx.x >> 6;    // 0..3
    const int lane = threadIdx.x & 63;
    const int cw   = ((bx & 15) << 4) | (wid << 2);   // wave's 4-ch base

    const int* roi = rois + r * 5;        // r uniform -> scalar loads
    const int b  = roi[0];
    const int x1 = roi[1] >> 4;           // floor(v/16), v in [0,800)
    const int y1 = roi[2] >> 4;
    const int x2 = roi[3] >> 4;
    const int y2 = roi[4] >> 4;
    const int h = y2 - y1 + 1;            // 1..50
    const int w = x2 - x1 + 1;            // 1..50

    // adaptive packing (all wave-uniform scalars)
    const int npacksh = (w <= 16) ? 2 : (w <= 32) ? 1 : 0;
    const int npack   = 1 << npacksh;     // 4 / 2 / 1 channels per pass
    const int ncolsh  = 6 - npacksh;      // 16 / 32 / 64 cols per channel
    const int ncol    = 1 << ncolsh;
    const int passes  = 4 >> npacksh;     // 1 / 2 / 4

    const int hc   = lane >> ncolsh;      // sub-channel within pass
    const int col  = lane & (ncol - 1);
    const int xcol = x1 + min(col, w - 1);   // clamped dup: max-safe, merged

    // band geometry (wave-uniform scalars)
    int sh[PH], nn[PH];
    int nmin = 64, nmax = 0;
    #pragma unroll
    for (int pp = 0; pp < PH; ++pp) {
        sh[pp] = y1 + (pp * h) / PH;
        nn[pp] = y1 + ((pp + 1) * h + PH - 1) / PH - sh[pp];   // 1..ceil+1
        nmin = min(nmin, nn[pp]);
        nmax = max(nmax, nn[pp]);
    }

    // reduce-phase lane mapping (lanes 49..63 idle there)
    const int cell = (lane < NCELL) ? lane : NCELL - 1;
    const int p  = cell / PW;             // magic mul
    const int q  = cell - p * PW;
    const int swr  = (q * w) / PW;
    const int ewr  = ((q + 1) * w + PW - 1) / PW;
    const int kwm1 = ewr - swr - 1;       // >= 0
    const int kmax = w / PW + 2;          // scalar bound, covers all windows

    #pragma unroll 1
    for (int pi = 0; pi < passes; ++pi) {
        const int chb = cw + (pi << npacksh);      // pass channel base
        const float* pl = features + ((size_t)b * C_ + chb + hc) * S_;

        const float* rp[PH];
        float cmv[PH];
        #pragma unroll
        for (int pp = 0; pp < PH; ++pp) {
            rp[pp]  = pl + sh[pp] * W_ + xcol;
            cmv[pp] = -INFINITY;
        }

        // main walk: 7 independent loads in flight per step
        for (int i = 0; i < nmin; ++i) {
            #pragma unroll
            for (int pp = 0; pp < PH; ++pp) {
                cmv[pp] = fmaxf(cmv[pp], *rp[pp]);
                rp[pp] += W_;
            }
        }
        // tail (<=2 iters, wave-uniform scalar conds)
        for (int i = nmin; i < nmax; ++i) {
            #pragma unroll
            for (int pp = 0; pp < PH; ++pp) {
                if (i < nn[pp]) {
                    cmv[pp] = fmaxf(cmv[pp], *rp[pp]);
                    rp[pp] += W_;
                }
            }
        }

        #pragma unroll
        for (int pp = 0; pp < PH; ++pp)            // lane-linear: 2-way, free
            strip[wid][pp][lane] = cmv[pp];
        asm volatile("s_waitcnt lgkmcnt(0)" ::: "memory");   // cross-lane RAW
        __builtin_amdgcn_sched_barrier(0);         // rule-18 fence

        #pragma unroll
        for (int hc2 = 0; hc2 < 4; ++hc2) {        // reduce pass channels
            if (hc2 < npack && lane < NCELL) {
                const float* cb2 = &strip[wid][p][(hc2 << ncolsh) + swr];
                float m = -INFINITY;
                for (int k = 0; k < kmax; ++k)     // scalar bound, clamped
                    m = fmaxf(m, cb2[min(k, kwm1)]);
                out[((size_t)r * C_ + chb + hc2) * NCELL + lane] = m;
            }
        }
        // keep next pass's strip writes after this pass's reads
        asm volatile("" ::: "memory");
        __builtin_amdgcn_sched_barrier(0);
    }
}

extern "C" void kernel_launch(void* const* d_in, const int* in_sizes, int n_in,
                              void* d_out, int out_size, void* d_ws, size_t ws_size,
                              hipStream_t stream) {
    const float* features = (const float*)d_in[0];
    const int*   rois     = (const int*)d_in[1];
    float*       out      = (float*)d_out;
    (void)d_ws; (void)ws_size;

    roi_pool_pack4<<<R_ * 16, 256, 0, stream>>>(features, rois, out);
}